// Round 6
// baseline (1133.549 us; speedup 1.0000x reference)
//
#include <hip/hip_runtime.h>

// MS-SSIM, 5 levels, 16x3x512x512 fp32, scalar fp32 out.
//
// R11: TWO launches (l0 -> tail), one dependency edge.
//  - l0_kernel: R9-proven tile (ssim0 + X1 store, 88us). Block (0,0,0)
//    also zeroes the tail's arrival counter (free reset, visible at the
//    dispatch boundary -> poison-proof, no memset node).
//  - tail_kernel (2784 blocks): L1 = hpass_direct on X1 (proven);
//    L2 = hpass_pool1 on X1 (proven); L3/L4 = pool2/pool3 gathered
//    DIRECTLY from X1 (R10-verified arithmetic trees; per-block X1
//    regions are L2-resident) -- no LDS staging, so LDS = 39KB and
//    4 blocks/CU (R9 tail had 50.7KB -> 3). Deep levels first.
//    The LAST arriving block (counter == 2783) runs the finalize:
//    accT read via agent-scope atomic loads (XCD-L2-coherence safe),
//    acc0 plain (written last dispatch). 
// R10 lesson: never recompute levels from img (431MB HBM fetch); X1
// (25MB) is the cache-resident source for everything deep.

#define NTHR 512

typedef float v4  __attribute__((ext_vector_type(4)));
typedef float v2f __attribute__((ext_vector_type(2)));

__device__ __forceinline__ float frcp(float x) { return __builtin_amdgcn_rcpf(x); }

#define GW_DEF const float GW[11] = {0.00102840f, 0.00759877f, 0.03600070f, \
    0.10936069f, 0.21300636f, 0.26601172f, 0.21300636f, 0.10936069f,        \
    0.03600070f, 0.00759877f, 0.00102840f};

__device__ __forceinline__ void conv11(const float* s, const float* d,
                                       v4& hs, v4& hd, v4& hss, v4& hdd)
{
    GW_DEF
    #pragma unroll
    for (int j = 0; j < 11; ++j) {
        float w = GW[j];
        v4 sv = {s[j], s[j+1], s[j+2], s[j+3]};
        v4 dv = {d[j], d[j+1], d[j+2], d[j+3]};
        v4 wsv = w * sv, wdv = w * dv;
        hs += wsv; hd += wdv; hss += wsv * sv; hdd += wdv * dv;
    }
}

// ---- h-pass: direct source rows (proven)
template<int TROWS>
__device__ void hpass_direct(const float* __restrict__ p1, const float* __restrict__ p2,
                             int H, int tx0, int ty0, v4* hb)
{
    constexpr int HR = TROWS + 10;
    for (int task = threadIdx.x; task < HR * 8; task += NTHR) {
        const int r = task >> 3, cg2 = task & 7;
        const int gr = ty0 + r;
        const int c0 = tx0 + cg2 * 4;
        v4 hs = 0.f, hd = 0.f, hss = 0.f, hdd = 0.f;
        if (gr < H) {
            float s[16], d[16];
            if (c0 + 16 <= H) {
                const float* pa = p1 + (size_t)gr * H + c0;
                const float* pb = p2 + (size_t)gr * H + c0;
                #pragma unroll
                for (int q = 0; q < 4; ++q) {
                    v4 va = *(const v4*)(pa + 4 * q);
                    v4 vb = *(const v4*)(pb + 4 * q);
                    v4 sv = va + vb, dv = va - vb;
                    s[4*q+0] = sv.x; s[4*q+1] = sv.y; s[4*q+2] = sv.z; s[4*q+3] = sv.w;
                    d[4*q+0] = dv.x; d[4*q+1] = dv.y; d[4*q+2] = dv.z; d[4*q+3] = dv.w;
                }
            } else {
                #pragma unroll
                for (int q = 0; q < 16; ++q) {
                    int cc = c0 + q;
                    float a = (cc < H) ? p1[(size_t)gr * H + cc] : 0.f;
                    float b = (cc < H) ? p2[(size_t)gr * H + cc] : 0.f;
                    s[q] = a + b; d[q] = a - b;
                }
            }
            conv11(s, d, hs, hd, hss, hdd);
        }
        v4* row = &hb[r * 33 + cg2 * 4];
        row[0] = (v4){hs.x, hd.x, hss.x, hdd.x};
        row[1] = (v4){hs.y, hd.y, hss.y, hdd.y};
        row[2] = (v4){hs.z, hd.z, hss.z, hdd.z};
        row[3] = (v4){hs.w, hd.w, hss.w, hdd.w};
    }
}

// ---- h-pass: pixels = pool1(src) inline (proven). H = level dim, src 2H.
template<int TROWS>
__device__ void hpass_pool1(const float* __restrict__ q1, const float* __restrict__ q2,
                            int H, int tx0, int ty0, v4* hb)
{
    constexpr int HR = TROWS + 10;
    const int HS = 2 * H;
    for (int task = threadIdx.x; task < HR * 8; task += NTHR) {
        const int r = task >> 3, cg2 = task & 7;
        const int gr = ty0 + r;
        const int c0 = tx0 + cg2 * 4;
        v4 hs = 0.f, hd = 0.f, hss = 0.f, hdd = 0.f;
        if (gr < H) {
            float s[16], d[16];
            const int iy = 2 * gr;
            if (c0 + 16 <= H) {
                const float* a0 = q1 + (size_t)iy * HS + 2 * c0;
                const float* b0 = q2 + (size_t)iy * HS + 2 * c0;
                #pragma unroll
                for (int q = 0; q < 8; ++q) {
                    v4 xa0 = *(const v4*)(a0 + 4 * q);
                    v4 xa1 = *(const v4*)(a0 + HS + 4 * q);
                    v4 xb0 = *(const v4*)(b0 + 4 * q);
                    v4 xb1 = *(const v4*)(b0 + HS + 4 * q);
                    float pa0 = 0.25f * ((xa0.x + xa0.y) + (xa1.x + xa1.y));
                    float pa1 = 0.25f * ((xa0.z + xa0.w) + (xa1.z + xa1.w));
                    float pb0 = 0.25f * ((xb0.x + xb0.y) + (xb1.x + xb1.y));
                    float pb1 = 0.25f * ((xb0.z + xb0.w) + (xb1.z + xb1.w));
                    s[2*q]   = pa0 + pb0; d[2*q]   = pa0 - pb0;
                    s[2*q+1] = pa1 + pb1; d[2*q+1] = pa1 - pb1;
                }
            } else {
                #pragma unroll
                for (int q = 0; q < 16; ++q) {
                    int cc = c0 + q;
                    float pa = 0.f, pb = 0.f;
                    if (cc < H) {
                        const float* qa = q1 + (size_t)iy * HS + 2 * cc;
                        const float* qb = q2 + (size_t)iy * HS + 2 * cc;
                        pa = 0.25f * ((qa[0] + qa[1]) + (qa[HS] + qa[HS + 1]));
                        pb = 0.25f * ((qb[0] + qb[1]) + (qb[HS] + qb[HS + 1]));
                    }
                    s[q] = pa + pb; d[q] = pa - pb;
                }
            }
            conv11(s, d, hs, hd, hss, hdd);
        }
        v4* row = &hb[r * 33 + cg2 * 4];
        row[0] = (v4){hs.x, hd.x, hss.x, hdd.x};
        row[1] = (v4){hs.y, hd.y, hss.y, hdd.y};
        row[2] = (v4){hs.z, hd.z, hss.z, hdd.z};
        row[3] = (v4){hs.w, hd.w, hss.w, hdd.w};
    }
}

// pool2 of a 4x4 src window at (4*gr, 4*cc) — R10-verified tree.
__device__ __forceinline__ float pool2g(const float* __restrict__ sp, int SD, int gr, int cc)
{
    const float* q = sp + (size_t)(4 * gr) * SD + 4 * cc;
    v4 r0 = *(const v4*)q;
    v4 r1 = *(const v4*)(q + SD);
    v4 r2 = *(const v4*)(q + 2 * SD);
    v4 r3 = *(const v4*)(q + 3 * SD);
    float a00 = 0.25f * ((r0.x + r0.y) + (r1.x + r1.y));
    float a01 = 0.25f * ((r0.z + r0.w) + (r1.z + r1.w));
    float a10 = 0.25f * ((r2.x + r2.y) + (r3.x + r3.y));
    float a11 = 0.25f * ((r2.z + r2.w) + (r3.z + r3.w));
    return 0.25f * ((a00 + a01) + (a10 + a11));
}

// pool3 of an 8x8 src window at (8*gr, 8*cc) — R10-verified tree.
__device__ __forceinline__ float pool3g(const float* __restrict__ sp, int SD, int gr, int cc)
{
    const float* q = sp + (size_t)(8 * gr) * SD + 8 * cc;
    float p2h[2][2];
    #pragma unroll
    for (int h = 0; h < 2; ++h) {
        const float* qq = q + (size_t)(4 * h) * SD;
        v4 A0 = *(const v4*)qq;
        v4 A1 = *(const v4*)(qq + SD);
        v4 A2 = *(const v4*)(qq + 2 * SD);
        v4 A3 = *(const v4*)(qq + 3 * SD);
        v4 B0 = *(const v4*)(qq + 4);
        v4 B1 = *(const v4*)(qq + SD + 4);
        v4 B2 = *(const v4*)(qq + 2 * SD + 4);
        v4 B3 = *(const v4*)(qq + 3 * SD + 4);
        float p00 = 0.25f * ((A0.x + A0.y) + (A1.x + A1.y));
        float p01 = 0.25f * ((A0.z + A0.w) + (A1.z + A1.w));
        float p10 = 0.25f * ((A2.x + A2.y) + (A3.x + A3.y));
        float p11 = 0.25f * ((A2.z + A2.w) + (A3.z + A3.w));
        float q00 = 0.25f * ((B0.x + B0.y) + (B1.x + B1.y));
        float q01 = 0.25f * ((B0.z + B0.w) + (B1.z + B1.w));
        float q10 = 0.25f * ((B2.x + B2.y) + (B3.x + B3.y));
        float q11 = 0.25f * ((B2.z + B2.w) + (B3.z + B3.w));
        p2h[h][0] = 0.25f * ((p00 + p01) + (p10 + p11));
        p2h[h][1] = 0.25f * ((q00 + q01) + (q10 + q11));
    }
    return 0.25f * ((p2h[0][0] + p2h[0][1]) + (p2h[1][0] + p2h[1][1]));
}

// ---- h-pass: pixels = pool2(X1) gathered from global. H = level dim.
template<int TROWS>
__device__ void hpass_pool2g(const float* __restrict__ q1, const float* __restrict__ q2,
                             int H, int tx0, int ty0, v4* hb)
{
    constexpr int HR = TROWS + 10;
    const int SD = 4 * H;
    for (int task = threadIdx.x; task < HR * 8; task += NTHR) {
        const int r = task >> 3, cg2 = task & 7;
        const int gr = ty0 + r;
        const int c0 = tx0 + cg2 * 4;
        v4 hs = 0.f, hd = 0.f, hss = 0.f, hdd = 0.f;
        if (gr < H) {
            float s[16], d[16];
            #pragma unroll
            for (int q = 0; q < 16; ++q) {
                int cc = c0 + q;
                float pa = 0.f, pb = 0.f;
                if (cc < H) {
                    pa = pool2g(q1, SD, gr, cc);
                    pb = pool2g(q2, SD, gr, cc);
                }
                s[q] = pa + pb; d[q] = pa - pb;
            }
            conv11(s, d, hs, hd, hss, hdd);
        }
        v4* row = &hb[r * 33 + cg2 * 4];
        row[0] = (v4){hs.x, hd.x, hss.x, hdd.x};
        row[1] = (v4){hs.y, hd.y, hss.y, hdd.y};
        row[2] = (v4){hs.z, hd.z, hss.z, hdd.z};
        row[3] = (v4){hs.w, hd.w, hss.w, hdd.w};
    }
}

// ---- h-pass: pixels = pool3(X1) gathered from global. H = level dim.
template<int TROWS>
__device__ void hpass_pool3g(const float* __restrict__ q1, const float* __restrict__ q2,
                             int H, int tx0, int ty0, v4* hb)
{
    constexpr int HR = TROWS + 10;
    const int SD = 8 * H;
    for (int task = threadIdx.x; task < HR * 8; task += NTHR) {
        const int r = task >> 3, cg2 = task & 7;
        const int gr = ty0 + r;
        const int c0 = tx0 + cg2 * 4;
        v4 hs = 0.f, hd = 0.f, hss = 0.f, hdd = 0.f;
        if (gr < H) {
            float s[16], d[16];
            #pragma unroll
            for (int q = 0; q < 16; ++q) {
                int cc = c0 + q;
                float pa = 0.f, pb = 0.f;
                if (cc < H) {
                    pa = pool3g(q1, SD, gr, cc);
                    pb = pool3g(q2, SD, gr, cc);
                }
                s[q] = pa + pb; d[q] = pa - pb;
            }
            conv11(s, d, hs, hd, hss, hdd);
        }
        v4* row = &hb[r * 33 + cg2 * 4];
        row[0] = (v4){hs.x, hd.x, hss.x, hdd.x};
        row[1] = (v4){hs.y, hd.y, hss.y, hdd.y};
        row[2] = (v4){hs.z, hd.z, hss.z, hdd.z};
        row[3] = (v4){hs.w, hd.w, hss.w, hdd.w};
    }
}

// ---- vertical pass + ssim/cs + block reduction (proven, verbatim)
template<int TROWS>
__device__ void vpass_reduce(int H, int tx0, int ty0, const v4* hb, float* red,
                             float* __restrict__ partS, float* __restrict__ partC)
{
    constexpr int OPT = TROWS * 32 / NTHR;
    constexpr int NW  = NTHR / 64;
    GW_DEF
    const float C1 = 1e-4f, C2 = 9e-4f;
    const int tid   = threadIdx.x;
    const int outHW = H - 10;
    const int col   = tid & 31;
    const int row0  = (tid >> 5) * OPT;
    const float colm = (tx0 + col < outHW) ? 1.f : 0.f;
    v4 A[OPT];
    #pragma unroll
    for (int k = 0; k < OPT; ++k) A[k] = 0.f;

    #pragma unroll
    for (int r = 0; r < OPT + 10; ++r) {
        v4 h = hb[(row0 + r) * 33 + col];
        #pragma unroll
        for (int k = 0; k < OPT; ++k) {
            const int j = r - k;
            if (j >= 0 && j < 11) A[k] += GW[j] * h;
        }
    }

    float ssim_t = 0.f, cs_t = 0.f;
    #pragma unroll
    for (int k = 0; k < OPT; ++k) {
        float mask = colm * ((ty0 + row0 + k < outHW) ? 1.f : 0.f);
        float mu_s = A[k].x, mu_d = A[k].y;
        float P = mu_s * mu_s, Q = mu_d * mu_d;
        float U = A[k].z - P, V = A[k].w - Q;
        float v1 = 0.5f * (U - V) + C2;
        float v2 = 0.5f * (U + V) + C2;
        float n1 = 0.5f * (P - Q) + C1;
        float d1 = 0.5f * (P + Q) + C1;
        float csv = v1 * frcp(v2);
        float ssv = n1 * csv * frcp(d1);
        cs_t   += mask * csv;
        ssim_t += mask * ssv;
    }

    #pragma unroll
    for (int off = 32; off > 0; off >>= 1) {
        ssim_t += __shfl_down(ssim_t, off);
        cs_t   += __shfl_down(cs_t, off);
    }
    int wave = tid >> 6, lane = tid & 63;
    if (lane == 0) { red[wave] = ssim_t; red[NW + wave] = cs_t; }
    __syncthreads();
    if (tid == 0) {
        float s = 0.f, c = 0.f;
        #pragma unroll
        for (int w = 0; w < NW; ++w) { s += red[w]; c += red[NW + w]; }
        partS[0] = s; partC[0] = c;
    }
}

// ---- level 0: ssim0 + X1 store (R9-proven) + counter reset
__global__ __launch_bounds__(NTHR, 8) void l0_kernel(
    const float* __restrict__ img1, const float* __restrict__ img2,
    float* __restrict__ x1a, float* __restrict__ x1b,
    float* __restrict__ accS, float* __restrict__ accC,
    unsigned int* __restrict__ ctr)
{
    __shared__ v4 hb[74 * 33];
    __shared__ float red[16];

    const int tid = threadIdx.x;
    const int nc  = blockIdx.z;
    const int tx0 = blockIdx.x * 32;
    const int ty0 = blockIdx.y * 64;
    const int H   = 512;
    const float* p1 = img1 + (size_t)nc * H * H;
    const float* p2 = img2 + (size_t)nc * H * H;

    if (blockIdx.x == 0 && blockIdx.y == 0 && blockIdx.z == 0 && tid == 0)
        *ctr = 0u;   // visible to tail at dispatch boundary; poison-proof

    {
        const int r = tid >> 4, c = tid & 15;          // 32 x 16
        const int iy = ty0 + 2 * r, ix = tx0 + 2 * c;
        v2f a0 = *(const v2f*)(p1 + (size_t)iy * H + ix);
        v2f a1 = *(const v2f*)(p1 + (size_t)(iy + 1) * H + ix);
        v2f b0 = *(const v2f*)(p2 + (size_t)iy * H + ix);
        v2f b1 = *(const v2f*)(p2 + (size_t)(iy + 1) * H + ix);
        size_t o = (size_t)nc * 256 * 256 + (size_t)((ty0 >> 1) + r) * 256 + ((tx0 >> 1) + c);
        x1a[o] = 0.25f * ((a0.x + a0.y) + (a1.x + a1.y));
        x1b[o] = 0.25f * ((b0.x + b0.y) + (b1.x + b1.y));
    }

    hpass_direct<64>(p1, p2, H, tx0, ty0, hb);
    __syncthreads();
    int fb = (int)blockIdx.x + 16 * ((int)blockIdx.y + 8 * nc);
    vpass_reduce<64>(H, tx0, ty0, hb, red, accS + fb, accC + fb);
}

// ---- levels 1..4 in one launch + fused last-block finalize
//   [0,96):      L4 H=32  T16 pool3 gather from X1
//   [96,480):    L3 H=64  T16 pool2 gather from X1
//   [480,1248):  L2 H=128 T32 pool1 inline from X1
//   [1248,2784): L1 H=256 T64 direct on X1
__global__ __launch_bounds__(NTHR, 8) void tail_kernel(
    const float* __restrict__ x1a, const float* __restrict__ x1b,
    const float* __restrict__ acc0S, const float* __restrict__ acc0C,
    float* __restrict__ accTS, float* __restrict__ accTC,
    unsigned int* __restrict__ ctr, float* __restrict__ out)
{
    __shared__ v4 hb[74 * 33];
    __shared__ float red[16];
    __shared__ float sm[10];
    __shared__ float wred[8];
    __shared__ int lastf;

    const int b = (int)blockIdx.x;
    const int tid = threadIdx.x;
    const size_t X1S = (size_t)256 * 256;

    if (b >= 1248) {                    // L1
        int lbk = b - 1248;
        int cx = lbk & 7, rem = lbk >> 3, cy = rem & 3, nc = rem >> 2;
        const float* p1 = x1a + (size_t)nc * X1S;
        const float* p2 = x1b + (size_t)nc * X1S;
        int tx0 = cx * 32, ty0 = cy * 64;
        hpass_direct<64>(p1, p2, 256, tx0, ty0, hb);
        __syncthreads();
        vpass_reduce<64>(256, tx0, ty0, hb, red, accTS + b, accTC + b);
    } else if (b >= 480) {              // L2
        int lbk = b - 480;
        int cx = lbk & 3, rem = lbk >> 2, cy = rem & 3, nc = rem >> 2;
        const float* p1 = x1a + (size_t)nc * X1S;
        const float* p2 = x1b + (size_t)nc * X1S;
        int tx0 = cx * 32, ty0 = cy * 32;
        hpass_pool1<32>(p1, p2, 128, tx0, ty0, hb);
        __syncthreads();
        vpass_reduce<32>(128, tx0, ty0, hb, red, accTS + b, accTC + b);
    } else if (b >= 96) {               // L3
        int lbk = b - 96;
        int cx = lbk & 1, rem = lbk >> 1, cy = rem & 3, nc = rem >> 2;
        const float* p1 = x1a + (size_t)nc * X1S;
        const float* p2 = x1b + (size_t)nc * X1S;
        int tx0 = cx * 32, ty0 = cy * 16;
        hpass_pool2g<16>(p1, p2, 64, tx0, ty0, hb);
        __syncthreads();
        vpass_reduce<16>(64, tx0, ty0, hb, red, accTS + b, accTC + b);
    } else {                            // L4
        int cy = b & 1, nc = b >> 1;
        const float* p1 = x1a + (size_t)nc * X1S;
        const float* p2 = x1b + (size_t)nc * X1S;
        int tx0 = 0, ty0 = cy * 16;
        hpass_pool3g<16>(p1, p2, 32, tx0, ty0, hb);
        __syncthreads();
        vpass_reduce<16>(32, tx0, ty0, hb, red, accTS + b, accTC + b);
    }

    // ---- last-arriving block runs the finalize
    __threadfence();
    if (tid == 0) {
        unsigned int old = __hip_atomic_fetch_add(ctr, 1u, __ATOMIC_ACQ_REL,
                                                  __HIP_MEMORY_SCOPE_AGENT);
        lastf = (old == 2783u) ? 1 : 0;
    }
    __syncthreads();
    if (!lastf) return;

    const int wave = tid >> 6, lane = tid & 63;
    const int st[5] = {0, 1248, 480, 96, 0};
    const int en[5] = {6144, 2784, 1248, 480, 96};

    for (int srs = 0; srs < 10; ++srs) {
        int l = srs >> 1;
        float p = 0.f;
        if (l == 0) {
            const float* base = (srs & 1) ? acc0C : acc0S;
            for (int i = tid; i < 6144; i += NTHR) p += base[i];
        } else {
            const float* base = (srs & 1) ? accTC : accTS;
            for (int i = st[l] + tid; i < en[l]; i += NTHR)
                p += __hip_atomic_load(&base[i], __ATOMIC_RELAXED,
                                       __HIP_MEMORY_SCOPE_AGENT);
        }
        #pragma unroll
        for (int o = 32; o > 0; o >>= 1) p += __shfl_down(p, o);
        if (lane == 0) wred[wave] = p;
        __syncthreads();
        if (tid == 0) {
            float t = 0.f;
            #pragma unroll
            for (int w = 0; w < 8; ++w) t += wred[w];
            sm[srs] = t;
        }
        __syncthreads();
    }

    if (tid == 0) {
        const float w[5] = {0.0448f, 0.2856f, 0.3001f, 0.2363f, 0.1333f};
        float ms[5], mc[5];
        for (int l = 0; l < 5; ++l) {
            int oh = (512 >> l) - 10;
            float cnt = 48.f * (float)oh * (float)oh;
            ms[l] = (sm[2 * l] / cnt + 1.f) * 0.5f;
            mc[l] = (sm[2 * l + 1] / cnt + 1.f) * 0.5f;
        }
        float p2 = powf(ms[4], w[4]);
        float r = 1.f;
        for (int i = 0; i < 4; ++i) r *= powf(mc[i], w[i]) * p2;
        out[0] = r;
    }
}

extern "C" void kernel_launch(void* const* d_in, const int* in_sizes, int n_in,
                              void* d_out, int out_size, void* d_ws, size_t ws_size,
                              hipStream_t stream)
{
    (void)in_sizes; (void)n_in; (void)out_size; (void)ws_size;
    const float* img1 = (const float*)d_in[0];
    const float* img2 = (const float*)d_in[1];
    float* out = (float*)d_out;
    float* ws  = (float*)d_ws;

    // workspace (floats): acc0S[6144] acc0C[6144] accTS[2784] accTC[2784]
    //                     ctr(+pad to 16 floats) X1a X1b
    float* acc0S = ws;
    float* acc0C = acc0S + 6144;
    float* accTS = acc0C + 6144;
    float* accTC = accTS + 2784;
    unsigned int* ctr = (unsigned int*)(accTC + 2784);   // float off 17856
    float* x1a = ws + 17872;                             // 16-float pad, 64B-aligned
    float* x1b = x1a + (size_t)48 * 256 * 256;

    l0_kernel<<<dim3(16, 8, 48), NTHR, 0, stream>>>(
        img1, img2, x1a, x1b, acc0S, acc0C, ctr);
    tail_kernel<<<dim3(2784), NTHR, 0, stream>>>(
        x1a, x1b, acc0S, acc0C, accTS, accTC, ctr, out);
}

// Round 7
// 473.620 us; speedup vs baseline: 2.3934x; 2.3934x over previous
//
#include <hip/hip_runtime.h>

// MS-SSIM, 5 levels, 16x3x512x512 fp32, scalar fp32 out.
//
// R12: 3 launches, rebalanced: k1 = L0 + L1 (L1 pools from img inline, so
// it does NOT depend on X1 and fuses into the same dispatch as L0);
// k2 = L2/L3/L4 from X1 only (1248 blocks); k3 = finalize.
// R11 lesson: NO per-block agent-scope fences/atomics for a fused
// finalize -- on MI355X (non-coherent per-XCD L2s) each ACQ_REL forces
// L2 writeback/invalidate => 10x slowdown (975us, VALUBusy 1.8%).
// Dependencies live at dispatch boundaries only.
// R10 lesson: deep levels must read X1 (25 MB, cache-resident), never img.
//
// k1 block map: [0,1536) L1-from-img | [1536,7680) L0 (+X1 store).
// k2 block map: [0,96) L4 | [96,480) L3 | [480,1248) L2.  (deep first)
// acc slots: k1 -> [0,7680), k2 -> [7680,8928). All written
// unconditionally -> workspace re-poison safe, no memset.

#define NTHR 512

typedef float v4  __attribute__((ext_vector_type(4)));
typedef float v2f __attribute__((ext_vector_type(2)));

__device__ __forceinline__ float frcp(float x) { return __builtin_amdgcn_rcpf(x); }

#define GW_DEF const float GW[11] = {0.00102840f, 0.00759877f, 0.03600070f, \
    0.10936069f, 0.21300636f, 0.26601172f, 0.21300636f, 0.10936069f,        \
    0.03600070f, 0.00759877f, 0.00102840f};

__device__ __forceinline__ void conv11(const float* s, const float* d,
                                       v4& hs, v4& hd, v4& hss, v4& hdd)
{
    GW_DEF
    #pragma unroll
    for (int j = 0; j < 11; ++j) {
        float w = GW[j];
        v4 sv = {s[j], s[j+1], s[j+2], s[j+3]};
        v4 dv = {d[j], d[j+1], d[j+2], d[j+3]};
        v4 wsv = w * sv, wdv = w * dv;
        hs += wsv; hd += wdv; hss += wsv * sv; hdd += wdv * dv;
    }
}

// ---- h-pass: direct source rows (proven)
template<int TROWS>
__device__ void hpass_direct(const float* __restrict__ p1, const float* __restrict__ p2,
                             int H, int tx0, int ty0, v4* hb)
{
    constexpr int HR = TROWS + 10;
    for (int task = threadIdx.x; task < HR * 8; task += NTHR) {
        const int r = task >> 3, cg2 = task & 7;
        const int gr = ty0 + r;
        const int c0 = tx0 + cg2 * 4;
        v4 hs = 0.f, hd = 0.f, hss = 0.f, hdd = 0.f;
        if (gr < H) {
            float s[16], d[16];
            if (c0 + 16 <= H) {
                const float* pa = p1 + (size_t)gr * H + c0;
                const float* pb = p2 + (size_t)gr * H + c0;
                #pragma unroll
                for (int q = 0; q < 4; ++q) {
                    v4 va = *(const v4*)(pa + 4 * q);
                    v4 vb = *(const v4*)(pb + 4 * q);
                    v4 sv = va + vb, dv = va - vb;
                    s[4*q+0] = sv.x; s[4*q+1] = sv.y; s[4*q+2] = sv.z; s[4*q+3] = sv.w;
                    d[4*q+0] = dv.x; d[4*q+1] = dv.y; d[4*q+2] = dv.z; d[4*q+3] = dv.w;
                }
            } else {
                #pragma unroll
                for (int q = 0; q < 16; ++q) {
                    int cc = c0 + q;
                    float a = (cc < H) ? p1[(size_t)gr * H + cc] : 0.f;
                    float b = (cc < H) ? p2[(size_t)gr * H + cc] : 0.f;
                    s[q] = a + b; d[q] = a - b;
                }
            }
            conv11(s, d, hs, hd, hss, hdd);
        }
        v4* row = &hb[r * 33 + cg2 * 4];
        row[0] = (v4){hs.x, hd.x, hss.x, hdd.x};
        row[1] = (v4){hs.y, hd.y, hss.y, hdd.y};
        row[2] = (v4){hs.z, hd.z, hss.z, hdd.z};
        row[3] = (v4){hs.w, hd.w, hss.w, hdd.w};
    }
}

// ---- h-pass: pixels = pool1(src) inline (proven). H = level dim, src 2H.
template<int TROWS>
__device__ void hpass_pool1(const float* __restrict__ q1, const float* __restrict__ q2,
                            int H, int tx0, int ty0, v4* hb)
{
    constexpr int HR = TROWS + 10;
    const int HS = 2 * H;
    for (int task = threadIdx.x; task < HR * 8; task += NTHR) {
        const int r = task >> 3, cg2 = task & 7;
        const int gr = ty0 + r;
        const int c0 = tx0 + cg2 * 4;
        v4 hs = 0.f, hd = 0.f, hss = 0.f, hdd = 0.f;
        if (gr < H) {
            float s[16], d[16];
            const int iy = 2 * gr;
            if (c0 + 16 <= H) {
                const float* a0 = q1 + (size_t)iy * HS + 2 * c0;
                const float* b0 = q2 + (size_t)iy * HS + 2 * c0;
                #pragma unroll
                for (int q = 0; q < 8; ++q) {
                    v4 xa0 = *(const v4*)(a0 + 4 * q);
                    v4 xa1 = *(const v4*)(a0 + HS + 4 * q);
                    v4 xb0 = *(const v4*)(b0 + 4 * q);
                    v4 xb1 = *(const v4*)(b0 + HS + 4 * q);
                    float pa0 = 0.25f * ((xa0.x + xa0.y) + (xa1.x + xa1.y));
                    float pa1 = 0.25f * ((xa0.z + xa0.w) + (xa1.z + xa1.w));
                    float pb0 = 0.25f * ((xb0.x + xb0.y) + (xb1.x + xb1.y));
                    float pb1 = 0.25f * ((xb0.z + xb0.w) + (xb1.z + xb1.w));
                    s[2*q]   = pa0 + pb0; d[2*q]   = pa0 - pb0;
                    s[2*q+1] = pa1 + pb1; d[2*q+1] = pa1 - pb1;
                }
            } else {
                #pragma unroll
                for (int q = 0; q < 16; ++q) {
                    int cc = c0 + q;
                    float pa = 0.f, pb = 0.f;
                    if (cc < H) {
                        const float* qa = q1 + (size_t)iy * HS + 2 * cc;
                        const float* qb = q2 + (size_t)iy * HS + 2 * cc;
                        pa = 0.25f * ((qa[0] + qa[1]) + (qa[HS] + qa[HS + 1]));
                        pb = 0.25f * ((qb[0] + qb[1]) + (qb[HS] + qb[HS + 1]));
                    }
                    s[q] = pa + pb; d[q] = pa - pb;
                }
            }
            conv11(s, d, hs, hd, hss, hdd);
        }
        v4* row = &hb[r * 33 + cg2 * 4];
        row[0] = (v4){hs.x, hd.x, hss.x, hdd.x};
        row[1] = (v4){hs.y, hd.y, hss.y, hdd.y};
        row[2] = (v4){hs.z, hd.z, hss.z, hdd.z};
        row[3] = (v4){hs.w, hd.w, hss.w, hdd.w};
    }
}

// pool2 of a 4x4 src window at (4*gr, 4*cc) — verified tree.
__device__ __forceinline__ float pool2g(const float* __restrict__ sp, int SD, int gr, int cc)
{
    const float* q = sp + (size_t)(4 * gr) * SD + 4 * cc;
    v4 r0 = *(const v4*)q;
    v4 r1 = *(const v4*)(q + SD);
    v4 r2 = *(const v4*)(q + 2 * SD);
    v4 r3 = *(const v4*)(q + 3 * SD);
    float a00 = 0.25f * ((r0.x + r0.y) + (r1.x + r1.y));
    float a01 = 0.25f * ((r0.z + r0.w) + (r1.z + r1.w));
    float a10 = 0.25f * ((r2.x + r2.y) + (r3.x + r3.y));
    float a11 = 0.25f * ((r2.z + r2.w) + (r3.z + r3.w));
    return 0.25f * ((a00 + a01) + (a10 + a11));
}

// pool3 of an 8x8 src window at (8*gr, 8*cc) — verified tree.
__device__ __forceinline__ float pool3g(const float* __restrict__ sp, int SD, int gr, int cc)
{
    const float* q = sp + (size_t)(8 * gr) * SD + 8 * cc;
    float p2h[2][2];
    #pragma unroll
    for (int h = 0; h < 2; ++h) {
        const float* qq = q + (size_t)(4 * h) * SD;
        v4 A0 = *(const v4*)qq;
        v4 A1 = *(const v4*)(qq + SD);
        v4 A2 = *(const v4*)(qq + 2 * SD);
        v4 A3 = *(const v4*)(qq + 3 * SD);
        v4 B0 = *(const v4*)(qq + 4);
        v4 B1 = *(const v4*)(qq + SD + 4);
        v4 B2 = *(const v4*)(qq + 2 * SD + 4);
        v4 B3 = *(const v4*)(qq + 3 * SD + 4);
        float p00 = 0.25f * ((A0.x + A0.y) + (A1.x + A1.y));
        float p01 = 0.25f * ((A0.z + A0.w) + (A1.z + A1.w));
        float p10 = 0.25f * ((A2.x + A2.y) + (A3.x + A3.y));
        float p11 = 0.25f * ((A2.z + A2.w) + (A3.z + A3.w));
        float q00 = 0.25f * ((B0.x + B0.y) + (B1.x + B1.y));
        float q01 = 0.25f * ((B0.z + B0.w) + (B1.z + B1.w));
        float q10 = 0.25f * ((B2.x + B2.y) + (B3.x + B3.y));
        float q11 = 0.25f * ((B2.z + B2.w) + (B3.z + B3.w));
        p2h[h][0] = 0.25f * ((p00 + p01) + (p10 + p11));
        p2h[h][1] = 0.25f * ((q00 + q01) + (q10 + q11));
    }
    return 0.25f * ((p2h[0][0] + p2h[0][1]) + (p2h[1][0] + p2h[1][1]));
}

// ---- h-pass: pixels = pool2(X1) gathered from global. H = level dim.
template<int TROWS>
__device__ void hpass_pool2g(const float* __restrict__ q1, const float* __restrict__ q2,
                             int H, int tx0, int ty0, v4* hb)
{
    constexpr int HR = TROWS + 10;
    const int SD = 4 * H;
    for (int task = threadIdx.x; task < HR * 8; task += NTHR) {
        const int r = task >> 3, cg2 = task & 7;
        const int gr = ty0 + r;
        const int c0 = tx0 + cg2 * 4;
        v4 hs = 0.f, hd = 0.f, hss = 0.f, hdd = 0.f;
        if (gr < H) {
            float s[16], d[16];
            #pragma unroll
            for (int q = 0; q < 16; ++q) {
                int cc = c0 + q;
                float pa = 0.f, pb = 0.f;
                if (cc < H) {
                    pa = pool2g(q1, SD, gr, cc);
                    pb = pool2g(q2, SD, gr, cc);
                }
                s[q] = pa + pb; d[q] = pa - pb;
            }
            conv11(s, d, hs, hd, hss, hdd);
        }
        v4* row = &hb[r * 33 + cg2 * 4];
        row[0] = (v4){hs.x, hd.x, hss.x, hdd.x};
        row[1] = (v4){hs.y, hd.y, hss.y, hdd.y};
        row[2] = (v4){hs.z, hd.z, hss.z, hdd.z};
        row[3] = (v4){hs.w, hd.w, hss.w, hdd.w};
    }
}

// ---- h-pass: pixels = pool3(X1) gathered from global. H = level dim.
template<int TROWS>
__device__ void hpass_pool3g(const float* __restrict__ q1, const float* __restrict__ q2,
                             int H, int tx0, int ty0, v4* hb)
{
    constexpr int HR = TROWS + 10;
    const int SD = 8 * H;
    for (int task = threadIdx.x; task < HR * 8; task += NTHR) {
        const int r = task >> 3, cg2 = task & 7;
        const int gr = ty0 + r;
        const int c0 = tx0 + cg2 * 4;
        v4 hs = 0.f, hd = 0.f, hss = 0.f, hdd = 0.f;
        if (gr < H) {
            float s[16], d[16];
            #pragma unroll
            for (int q = 0; q < 16; ++q) {
                int cc = c0 + q;
                float pa = 0.f, pb = 0.f;
                if (cc < H) {
                    pa = pool3g(q1, SD, gr, cc);
                    pb = pool3g(q2, SD, gr, cc);
                }
                s[q] = pa + pb; d[q] = pa - pb;
            }
            conv11(s, d, hs, hd, hss, hdd);
        }
        v4* row = &hb[r * 33 + cg2 * 4];
        row[0] = (v4){hs.x, hd.x, hss.x, hdd.x};
        row[1] = (v4){hs.y, hd.y, hss.y, hdd.y};
        row[2] = (v4){hs.z, hd.z, hss.z, hdd.z};
        row[3] = (v4){hs.w, hd.w, hss.w, hdd.w};
    }
}

// ---- vertical pass + ssim/cs + block reduction (proven, verbatim)
template<int TROWS>
__device__ void vpass_reduce(int H, int tx0, int ty0, const v4* hb, float* red,
                             float* __restrict__ partS, float* __restrict__ partC)
{
    constexpr int OPT = TROWS * 32 / NTHR;
    constexpr int NW  = NTHR / 64;
    GW_DEF
    const float C1 = 1e-4f, C2 = 9e-4f;
    const int tid   = threadIdx.x;
    const int outHW = H - 10;
    const int col   = tid & 31;
    const int row0  = (tid >> 5) * OPT;
    const float colm = (tx0 + col < outHW) ? 1.f : 0.f;
    v4 A[OPT];
    #pragma unroll
    for (int k = 0; k < OPT; ++k) A[k] = 0.f;

    #pragma unroll
    for (int r = 0; r < OPT + 10; ++r) {
        v4 h = hb[(row0 + r) * 33 + col];
        #pragma unroll
        for (int k = 0; k < OPT; ++k) {
            const int j = r - k;
            if (j >= 0 && j < 11) A[k] += GW[j] * h;
        }
    }

    float ssim_t = 0.f, cs_t = 0.f;
    #pragma unroll
    for (int k = 0; k < OPT; ++k) {
        float mask = colm * ((ty0 + row0 + k < outHW) ? 1.f : 0.f);
        float mu_s = A[k].x, mu_d = A[k].y;
        float P = mu_s * mu_s, Q = mu_d * mu_d;
        float U = A[k].z - P, V = A[k].w - Q;
        float v1 = 0.5f * (U - V) + C2;
        float v2 = 0.5f * (U + V) + C2;
        float n1 = 0.5f * (P - Q) + C1;
        float d1 = 0.5f * (P + Q) + C1;
        float csv = v1 * frcp(v2);
        float ssv = n1 * csv * frcp(d1);
        cs_t   += mask * csv;
        ssim_t += mask * ssv;
    }

    #pragma unroll
    for (int off = 32; off > 0; off >>= 1) {
        ssim_t += __shfl_down(ssim_t, off);
        cs_t   += __shfl_down(cs_t, off);
    }
    int wave = tid >> 6, lane = tid & 63;
    if (lane == 0) { red[wave] = ssim_t; red[NW + wave] = cs_t; }
    __syncthreads();
    if (tid == 0) {
        float s = 0.f, c = 0.f;
        #pragma unroll
        for (int w = 0; w < NW; ++w) { s += red[w]; c += red[NW + w]; }
        partS[0] = s; partC[0] = c;
    }
}

// ---- k1: L0 (+X1 store) fused with L1-from-img
//   [0,1536):    L1 H=256 T64, hpass_pool1 on img (pool1(img)==X1 bitwise)
//   [1536,7680): L0 H=512 T64, hpass_direct on img + X1 store
__global__ __launch_bounds__(NTHR, 8) void combo_kernel(
    const float* __restrict__ img1, const float* __restrict__ img2,
    float* __restrict__ x1a, float* __restrict__ x1b,
    float* __restrict__ accS, float* __restrict__ accC)
{
    __shared__ v4 hb[74 * 33];
    __shared__ float red[16];

    const int b   = (int)blockIdx.x;
    const int tid = threadIdx.x;
    const size_t IMS = (size_t)512 * 512;

    if (b < 1536) {                     // L1 from img
        int cx = b & 7, rem = b >> 3, cy = rem & 3, nc = rem >> 2;
        const float* p1 = img1 + (size_t)nc * IMS;
        const float* p2 = img2 + (size_t)nc * IMS;
        int tx0 = cx * 32, ty0 = cy * 64;
        hpass_pool1<64>(p1, p2, 256, tx0, ty0, hb);
        __syncthreads();
        vpass_reduce<64>(256, tx0, ty0, hb, red, accS + b, accC + b);
    } else {                            // L0 + X1 store
        int lbk = b - 1536;
        int cx = lbk & 15, rem = lbk >> 4, cy = rem & 7, nc = rem >> 3;
        const float* p1 = img1 + (size_t)nc * IMS;
        const float* p2 = img2 + (size_t)nc * IMS;
        int tx0 = cx * 32, ty0 = cy * 64;
        {
            const int r = tid >> 4, c = tid & 15;      // 32 x 16
            const int iy = ty0 + 2 * r, ix = tx0 + 2 * c;
            v2f a0 = *(const v2f*)(p1 + (size_t)iy * 512 + ix);
            v2f a1 = *(const v2f*)(p1 + (size_t)(iy + 1) * 512 + ix);
            v2f b0 = *(const v2f*)(p2 + (size_t)iy * 512 + ix);
            v2f b1 = *(const v2f*)(p2 + (size_t)(iy + 1) * 512 + ix);
            size_t o = (size_t)nc * 256 * 256 + (size_t)((ty0 >> 1) + r) * 256 + ((tx0 >> 1) + c);
            x1a[o] = 0.25f * ((a0.x + a0.y) + (a1.x + a1.y));
            x1b[o] = 0.25f * ((b0.x + b0.y) + (b1.x + b1.y));
        }
        hpass_direct<64>(p1, p2, 512, tx0, ty0, hb);
        __syncthreads();
        vpass_reduce<64>(512, tx0, ty0, hb, red, accS + b, accC + b);
    }
}

// ---- k2: L2/L3/L4 from X1, deep-first. Slots at 7680 + b.
//   [0,96):    L4 H=32  T16 pool3g | [96,480): L3 H=64 T16 pool2g |
//   [480,1248): L2 H=128 T32 pool1 inline
__global__ __launch_bounds__(NTHR, 8) void deep_kernel(
    const float* __restrict__ x1a, const float* __restrict__ x1b,
    float* __restrict__ accS, float* __restrict__ accC)
{
    __shared__ v4 hb[74 * 33];
    __shared__ float red[16];

    const int b = (int)blockIdx.x;
    const size_t X1S = (size_t)256 * 256;
    float* pS = accS + 7680 + b;
    float* pC = accC + 7680 + b;

    if (b >= 480) {                     // L2
        int lbk = b - 480;
        int cx = lbk & 3, rem = lbk >> 2, cy = rem & 3, nc = rem >> 2;
        const float* p1 = x1a + (size_t)nc * X1S;
        const float* p2 = x1b + (size_t)nc * X1S;
        int tx0 = cx * 32, ty0 = cy * 32;
        hpass_pool1<32>(p1, p2, 128, tx0, ty0, hb);
        __syncthreads();
        vpass_reduce<32>(128, tx0, ty0, hb, red, pS, pC);
    } else if (b >= 96) {               // L3
        int lbk = b - 96;
        int cx = lbk & 1, rem = lbk >> 1, cy = rem & 3, nc = rem >> 2;
        const float* p1 = x1a + (size_t)nc * X1S;
        const float* p2 = x1b + (size_t)nc * X1S;
        int tx0 = cx * 32, ty0 = cy * 16;
        hpass_pool2g<16>(p1, p2, 64, tx0, ty0, hb);
        __syncthreads();
        vpass_reduce<16>(64, tx0, ty0, hb, red, pS, pC);
    } else {                            // L4
        int cy = b & 1, nc = b >> 1;
        const float* p1 = x1a + (size_t)nc * X1S;
        const float* p2 = x1b + (size_t)nc * X1S;
        int tx0 = 0, ty0 = cy * 16;
        hpass_pool3g<16>(p1, p2, 32, tx0, ty0, hb);
        __syncthreads();
        vpass_reduce<16>(32, tx0, ty0, hb, red, pS, pC);
    }
}

// ---- k3: finalize (plain loads; deps at dispatch boundary)
__global__ void finalize_kernel(const float* __restrict__ accS, const float* __restrict__ accC,
                                float* __restrict__ out)
{
    __shared__ float sm[10];
    __shared__ float wred[8];
    const int tid  = (int)threadIdx.x;
    const int wave = tid >> 6, lane = tid & 63;
    // level -> slot ranges: L0 [1536,7680) L1 [0,1536) L2 [8160,8928)
    //                       L3 [7776,8160) L4 [7680,7776)
    const int st[5] = {1536, 0, 8160, 7776, 7680};
    const int en[5] = {7680, 1536, 8928, 8160, 7776};

    for (int srs = 0; srs < 10; ++srs) {
        int l = srs >> 1;
        const float* base = (srs & 1) ? accC : accS;
        float p = 0.f;
        for (int i = st[l] + tid; i < en[l]; i += NTHR) p += base[i];
        #pragma unroll
        for (int o = 32; o > 0; o >>= 1) p += __shfl_down(p, o);
        if (lane == 0) wred[wave] = p;
        __syncthreads();
        if (tid == 0) {
            float t = 0.f;
            #pragma unroll
            for (int w = 0; w < 8; ++w) t += wred[w];
            sm[srs] = t;
        }
        __syncthreads();
    }

    if (tid == 0) {
        const float w[5] = {0.0448f, 0.2856f, 0.3001f, 0.2363f, 0.1333f};
        float ms[5], mc[5];
        for (int l = 0; l < 5; ++l) {
            int oh = (512 >> l) - 10;
            float cnt = 48.f * (float)oh * (float)oh;
            ms[l] = (sm[2 * l] / cnt + 1.f) * 0.5f;
            mc[l] = (sm[2 * l + 1] / cnt + 1.f) * 0.5f;
        }
        float p2 = powf(ms[4], w[4]);
        float r = 1.f;
        for (int i = 0; i < 4; ++i) r *= powf(mc[i], w[i]) * p2;
        out[0] = r;
    }
}

extern "C" void kernel_launch(void* const* d_in, const int* in_sizes, int n_in,
                              void* d_out, int out_size, void* d_ws, size_t ws_size,
                              hipStream_t stream)
{
    (void)in_sizes; (void)n_in; (void)out_size; (void)ws_size;
    const float* img1 = (const float*)d_in[0];
    const float* img2 = (const float*)d_in[1];
    float* out = (float*)d_out;
    float* ws  = (float*)d_ws;

    // workspace (floats): accS[8928] accC[8928] X1a X1b
    float* accS = ws;
    float* accC = accS + 8928;
    float* x1a  = accC + 8928;          // 17856 floats = 64B-aligned
    float* x1b  = x1a + (size_t)48 * 256 * 256;

    combo_kernel<<<dim3(7680), NTHR, 0, stream>>>(img1, img2, x1a, x1b, accS, accC);
    deep_kernel<<<dim3(1248), NTHR, 0, stream>>>(x1a, x1b, accS, accC);
    finalize_kernel<<<1, NTHR, 0, stream>>>(accS, accC, out);
}

// Round 8
// 222.327 us; speedup vs baseline: 5.0986x; 2.1303x over previous
//
#include <hip/hip_runtime.h>

// MS-SSIM, 5 levels, 16x3x512x512 fp32, scalar fp32 out.
//
// R13 = R9 (champion, 225.9us) with a slimmer tail:
//  - l0_kernel: L0 tile + X1 store (proven 88us). 
//  - tail_kernel (2784 blocks, deep-first): L1 direct on X1 (proven),
//    L2 pool1-inline on X1 (proven); L3/L4 now stage the LEVEL PIXELS
//    (26x44 region of X3/X4, pitch 45) via the verified pool2g/pool3g
//    trees -- one value per thread, fully coalesced X1 reads -- then a
//    direct-from-LDS h-pass. T16 LDS: 50.7KB -> 23.1KB, so the whole
//    tail unions into the same 39,424B LDS block as l0.
//  - finalize: proven.
// R12 lessons: per-output global gathers in the h-pass are latency-bound
// and amplify HBM 10x (compute pooled values ONCE, coalesced, into LDS);
// L1 must read X1, not img. R11 lesson: no per-block agent-scope
// atomics/fences; deps live at dispatch boundaries only.

#define NTHR 512

typedef float v4  __attribute__((ext_vector_type(4)));
typedef float v2f __attribute__((ext_vector_type(2)));

__device__ __forceinline__ float frcp(float x) { return __builtin_amdgcn_rcpf(x); }

#define GW_DEF const float GW[11] = {0.00102840f, 0.00759877f, 0.03600070f, \
    0.10936069f, 0.21300636f, 0.26601172f, 0.21300636f, 0.10936069f,        \
    0.03600070f, 0.00759877f, 0.00102840f};

__device__ __forceinline__ void conv11(const float* s, const float* d,
                                       v4& hs, v4& hd, v4& hss, v4& hdd)
{
    GW_DEF
    #pragma unroll
    for (int j = 0; j < 11; ++j) {
        float w = GW[j];
        v4 sv = {s[j], s[j+1], s[j+2], s[j+3]};
        v4 dv = {d[j], d[j+1], d[j+2], d[j+3]};
        v4 wsv = w * sv, wdv = w * dv;
        hs += wsv; hd += wdv; hss += wsv * sv; hdd += wdv * dv;
    }
}

// ---- h-pass: direct source rows (proven)
template<int TROWS>
__device__ void hpass_direct(const float* __restrict__ p1, const float* __restrict__ p2,
                             int H, int tx0, int ty0, v4* hb)
{
    constexpr int HR = TROWS + 10;
    for (int task = threadIdx.x; task < HR * 8; task += NTHR) {
        const int r = task >> 3, cg2 = task & 7;
        const int gr = ty0 + r;
        const int c0 = tx0 + cg2 * 4;
        v4 hs = 0.f, hd = 0.f, hss = 0.f, hdd = 0.f;
        if (gr < H) {
            float s[16], d[16];
            if (c0 + 16 <= H) {
                const float* pa = p1 + (size_t)gr * H + c0;
                const float* pb = p2 + (size_t)gr * H + c0;
                #pragma unroll
                for (int q = 0; q < 4; ++q) {
                    v4 va = *(const v4*)(pa + 4 * q);
                    v4 vb = *(const v4*)(pb + 4 * q);
                    v4 sv = va + vb, dv = va - vb;
                    s[4*q+0] = sv.x; s[4*q+1] = sv.y; s[4*q+2] = sv.z; s[4*q+3] = sv.w;
                    d[4*q+0] = dv.x; d[4*q+1] = dv.y; d[4*q+2] = dv.z; d[4*q+3] = dv.w;
                }
            } else {
                #pragma unroll
                for (int q = 0; q < 16; ++q) {
                    int cc = c0 + q;
                    float a = (cc < H) ? p1[(size_t)gr * H + cc] : 0.f;
                    float b = (cc < H) ? p2[(size_t)gr * H + cc] : 0.f;
                    s[q] = a + b; d[q] = a - b;
                }
            }
            conv11(s, d, hs, hd, hss, hdd);
        }
        v4* row = &hb[r * 33 + cg2 * 4];
        row[0] = (v4){hs.x, hd.x, hss.x, hdd.x};
        row[1] = (v4){hs.y, hd.y, hss.y, hdd.y};
        row[2] = (v4){hs.z, hd.z, hss.z, hdd.z};
        row[3] = (v4){hs.w, hd.w, hss.w, hdd.w};
    }
}

// ---- h-pass: pixels = pool1(src) inline (proven). H = level dim, src 2H.
template<int TROWS>
__device__ void hpass_pool1(const float* __restrict__ q1, const float* __restrict__ q2,
                            int H, int tx0, int ty0, v4* hb)
{
    constexpr int HR = TROWS + 10;
    const int HS = 2 * H;
    for (int task = threadIdx.x; task < HR * 8; task += NTHR) {
        const int r = task >> 3, cg2 = task & 7;
        const int gr = ty0 + r;
        const int c0 = tx0 + cg2 * 4;
        v4 hs = 0.f, hd = 0.f, hss = 0.f, hdd = 0.f;
        if (gr < H) {
            float s[16], d[16];
            const int iy = 2 * gr;
            if (c0 + 16 <= H) {
                const float* a0 = q1 + (size_t)iy * HS + 2 * c0;
                const float* b0 = q2 + (size_t)iy * HS + 2 * c0;
                #pragma unroll
                for (int q = 0; q < 8; ++q) {
                    v4 xa0 = *(const v4*)(a0 + 4 * q);
                    v4 xa1 = *(const v4*)(a0 + HS + 4 * q);
                    v4 xb0 = *(const v4*)(b0 + 4 * q);
                    v4 xb1 = *(const v4*)(b0 + HS + 4 * q);
                    float pa0 = 0.25f * ((xa0.x + xa0.y) + (xa1.x + xa1.y));
                    float pa1 = 0.25f * ((xa0.z + xa0.w) + (xa1.z + xa1.w));
                    float pb0 = 0.25f * ((xb0.x + xb0.y) + (xb1.x + xb1.y));
                    float pb1 = 0.25f * ((xb0.z + xb0.w) + (xb1.z + xb1.w));
                    s[2*q]   = pa0 + pb0; d[2*q]   = pa0 - pb0;
                    s[2*q+1] = pa1 + pb1; d[2*q+1] = pa1 - pb1;
                }
            } else {
                #pragma unroll
                for (int q = 0; q < 16; ++q) {
                    int cc = c0 + q;
                    float pa = 0.f, pb = 0.f;
                    if (cc < H) {
                        const float* qa = q1 + (size_t)iy * HS + 2 * cc;
                        const float* qb = q2 + (size_t)iy * HS + 2 * cc;
                        pa = 0.25f * ((qa[0] + qa[1]) + (qa[HS] + qa[HS + 1]));
                        pb = 0.25f * ((qb[0] + qb[1]) + (qb[HS] + qb[HS + 1]));
                    }
                    s[q] = pa + pb; d[q] = pa - pb;
                }
            }
            conv11(s, d, hs, hd, hss, hdd);
        }
        v4* row = &hb[r * 33 + cg2 * 4];
        row[0] = (v4){hs.x, hd.x, hss.x, hdd.x};
        row[1] = (v4){hs.y, hd.y, hss.y, hdd.y};
        row[2] = (v4){hs.z, hd.z, hss.z, hdd.z};
        row[3] = (v4){hs.w, hd.w, hss.w, hdd.w};
    }
}

// pool2 of a 4x4 src window at (4*gr, 4*cc) — verified tree (R11 L3).
__device__ __forceinline__ float pool2g(const float* __restrict__ sp, int SD, int gr, int cc)
{
    const float* q = sp + (size_t)(4 * gr) * SD + 4 * cc;
    v4 r0 = *(const v4*)q;
    v4 r1 = *(const v4*)(q + SD);
    v4 r2 = *(const v4*)(q + 2 * SD);
    v4 r3 = *(const v4*)(q + 3 * SD);
    float a00 = 0.25f * ((r0.x + r0.y) + (r1.x + r1.y));
    float a01 = 0.25f * ((r0.z + r0.w) + (r1.z + r1.w));
    float a10 = 0.25f * ((r2.x + r2.y) + (r3.x + r3.y));
    float a11 = 0.25f * ((r2.z + r2.w) + (r3.z + r3.w));
    return 0.25f * ((a00 + a01) + (a10 + a11));
}

// pool3 of an 8x8 src window at (8*gr, 8*cc) — verified tree (R11 L4).
__device__ __forceinline__ float pool3g(const float* __restrict__ sp, int SD, int gr, int cc)
{
    const float* q = sp + (size_t)(8 * gr) * SD + 8 * cc;
    float p2h[2][2];
    #pragma unroll
    for (int h = 0; h < 2; ++h) {
        const float* qq = q + (size_t)(4 * h) * SD;
        v4 A0 = *(const v4*)qq;
        v4 A1 = *(const v4*)(qq + SD);
        v4 A2 = *(const v4*)(qq + 2 * SD);
        v4 A3 = *(const v4*)(qq + 3 * SD);
        v4 B0 = *(const v4*)(qq + 4);
        v4 B1 = *(const v4*)(qq + SD + 4);
        v4 B2 = *(const v4*)(qq + 2 * SD + 4);
        v4 B3 = *(const v4*)(qq + 3 * SD + 4);
        float p00 = 0.25f * ((A0.x + A0.y) + (A1.x + A1.y));
        float p01 = 0.25f * ((A0.z + A0.w) + (A1.z + A1.w));
        float p10 = 0.25f * ((A2.x + A2.y) + (A3.x + A3.y));
        float p11 = 0.25f * ((A2.z + A2.w) + (A3.z + A3.w));
        float q00 = 0.25f * ((B0.x + B0.y) + (B1.x + B1.y));
        float q01 = 0.25f * ((B0.z + B0.w) + (B1.z + B1.w));
        float q10 = 0.25f * ((B2.x + B2.y) + (B3.x + B3.y));
        float q11 = 0.25f * ((B2.z + B2.w) + (B3.z + B3.w));
        p2h[h][0] = 0.25f * ((p00 + p01) + (p10 + p11));
        p2h[h][1] = 0.25f * ((q00 + q01) + (q10 + q11));
    }
    return 0.25f * ((p2h[0][0] + p2h[0][1]) + (p2h[1][0] + p2h[1][1]));
}

// Stage 26x44 region (pitch 45) of LEVEL pixels = pool2(X1). One value
// per thread, coalesced X1 reads. H = level dim (64); X1 dim = 4*H.
__device__ void stage_x3(const float* __restrict__ s1, const float* __restrict__ s2,
                         int H, int tx0, int ty0, float* la, float* lb)
{
    const int SD = 4 * H;
    for (int t = threadIdx.x; t < 2 * 26 * 44; t += NTHR) {
        int im = t >= 26 * 44; int tt = im ? t - 26 * 44 : t;
        int rr = tt / 44, cc = tt % 44;
        int y = ty0 + rr, x = tx0 + cc;
        const float* sp = im ? s2 : s1;
        float* lp = im ? lb : la;
        float v = 0.f;
        if (y < H && x < H) v = pool2g(sp, SD, y, x);
        lp[rr * 45 + cc] = v;
    }
}

// Stage 26x44 region of LEVEL pixels = pool3(X1). H = level dim (32).
__device__ void stage_x4(const float* __restrict__ s1, const float* __restrict__ s2,
                         int H, int tx0, int ty0, float* la, float* lb)
{
    const int SD = 8 * H;
    for (int t = threadIdx.x; t < 2 * 26 * 44; t += NTHR) {
        int im = t >= 26 * 44; int tt = im ? t - 26 * 44 : t;
        int rr = tt / 44, cc = tt % 44;
        int y = ty0 + rr, x = tx0 + cc;
        const float* sp = im ? s2 : s1;
        float* lp = im ? lb : la;
        float v = 0.f;
        if (y < H && x < H) v = pool3g(sp, SD, y, x);
        lp[rr * 45 + cc] = v;
    }
}

// ---- h-pass: level pixels already staged in LDS (26x44 region, pitch 45,
// origin (ty0, tx0); OOB staged as 0 == proven guarded-path behavior).
template<int TROWS>
__device__ void hpass_ldsdir(const float* la, const float* lb,
                             int H, int tx0, int ty0, v4* hb)
{
    constexpr int HR = TROWS + 10;
    (void)tx0;
    for (int task = threadIdx.x; task < HR * 8; task += NTHR) {
        const int r = task >> 3, cg2 = task & 7;
        const int gr = ty0 + r;
        const int c0 = cg2 * 4;              // local col base
        v4 hs = 0.f, hd = 0.f, hss = 0.f, hdd = 0.f;
        if (gr < H) {
            float s[16], d[16];
            #pragma unroll
            for (int q = 0; q < 16; ++q) {
                float pa = la[r * 45 + c0 + q];
                float pb = lb[r * 45 + c0 + q];
                s[q] = pa + pb; d[q] = pa - pb;
            }
            conv11(s, d, hs, hd, hss, hdd);
        }
        v4* row = &hb[r * 33 + cg2 * 4];
        row[0] = (v4){hs.x, hd.x, hss.x, hdd.x};
        row[1] = (v4){hs.y, hd.y, hss.y, hdd.y};
        row[2] = (v4){hs.z, hd.z, hss.z, hdd.z};
        row[3] = (v4){hs.w, hd.w, hss.w, hdd.w};
    }
}

// ---- vertical pass + ssim/cs + block reduction (proven, verbatim)
template<int TROWS>
__device__ void vpass_reduce(int H, int tx0, int ty0, const v4* hb, float* red,
                             float* __restrict__ partS, float* __restrict__ partC)
{
    constexpr int OPT = TROWS * 32 / NTHR;
    constexpr int NW  = NTHR / 64;
    GW_DEF
    const float C1 = 1e-4f, C2 = 9e-4f;
    const int tid   = threadIdx.x;
    const int outHW = H - 10;
    const int col   = tid & 31;
    const int row0  = (tid >> 5) * OPT;
    const float colm = (tx0 + col < outHW) ? 1.f : 0.f;
    v4 A[OPT];
    #pragma unroll
    for (int k = 0; k < OPT; ++k) A[k] = 0.f;

    #pragma unroll
    for (int r = 0; r < OPT + 10; ++r) {
        v4 h = hb[(row0 + r) * 33 + col];
        #pragma unroll
        for (int k = 0; k < OPT; ++k) {
            const int j = r - k;
            if (j >= 0 && j < 11) A[k] += GW[j] * h;
        }
    }

    float ssim_t = 0.f, cs_t = 0.f;
    #pragma unroll
    for (int k = 0; k < OPT; ++k) {
        float mask = colm * ((ty0 + row0 + k < outHW) ? 1.f : 0.f);
        float mu_s = A[k].x, mu_d = A[k].y;
        float P = mu_s * mu_s, Q = mu_d * mu_d;
        float U = A[k].z - P, V = A[k].w - Q;
        float v1 = 0.5f * (U - V) + C2;
        float v2 = 0.5f * (U + V) + C2;
        float n1 = 0.5f * (P - Q) + C1;
        float d1 = 0.5f * (P + Q) + C1;
        float csv = v1 * frcp(v2);
        float ssv = n1 * csv * frcp(d1);
        cs_t   += mask * csv;
        ssim_t += mask * ssv;
    }

    #pragma unroll
    for (int off = 32; off > 0; off >>= 1) {
        ssim_t += __shfl_down(ssim_t, off);
        cs_t   += __shfl_down(cs_t, off);
    }
    int wave = tid >> 6, lane = tid & 63;
    if (lane == 0) { red[wave] = ssim_t; red[NW + wave] = cs_t; }
    __syncthreads();
    if (tid == 0) {
        float s = 0.f, c = 0.f;
        #pragma unroll
        for (int w = 0; w < NW; ++w) { s += red[w]; c += red[NW + w]; }
        partS[0] = s; partC[0] = c;
    }
}

// ---- level 0: ssim0 + X1 store (proven)
__global__ __launch_bounds__(NTHR, 8) void l0_kernel(
    const float* __restrict__ img1, const float* __restrict__ img2,
    float* __restrict__ x1a, float* __restrict__ x1b,
    float* __restrict__ accS, float* __restrict__ accC)
{
    __shared__ v4 hb[74 * 33];
    __shared__ float red[16];

    const int tid = threadIdx.x;
    const int nc  = blockIdx.z;
    const int tx0 = blockIdx.x * 32;
    const int ty0 = blockIdx.y * 64;
    const int H   = 512;
    const float* p1 = img1 + (size_t)nc * H * H;
    const float* p2 = img2 + (size_t)nc * H * H;

    {
        const int r = tid >> 4, c = tid & 15;          // 32 x 16
        const int iy = ty0 + 2 * r, ix = tx0 + 2 * c;
        v2f a0 = *(const v2f*)(p1 + (size_t)iy * H + ix);
        v2f a1 = *(const v2f*)(p1 + (size_t)(iy + 1) * H + ix);
        v2f b0 = *(const v2f*)(p2 + (size_t)iy * H + ix);
        v2f b1 = *(const v2f*)(p2 + (size_t)(iy + 1) * H + ix);
        size_t o = (size_t)nc * 256 * 256 + (size_t)((ty0 >> 1) + r) * 256 + ((tx0 >> 1) + c);
        x1a[o] = 0.25f * ((a0.x + a0.y) + (a1.x + a1.y));
        x1b[o] = 0.25f * ((b0.x + b0.y) + (b1.x + b1.y));
    }

    hpass_direct<64>(p1, p2, H, tx0, ty0, hb);
    __syncthreads();
    int fb = (int)blockIdx.x + 16 * ((int)blockIdx.y + 8 * nc);
    vpass_reduce<64>(H, tx0, ty0, hb, red, accS + fb, accC + fb);
}

// ---- levels 1..4 in one launch, deep-first, all from X1
//   [0,96):      L4 H=32  T16 staged pool3(X1) -> LDS -> direct h-pass
//   [96,480):    L3 H=64  T16 staged pool2(X1) -> LDS -> direct h-pass
//   [480,1248):  L2 H=128 T32 pool1 inline from X1 (proven)
//   [1248,2784): L1 H=256 T64 direct on X1 (proven)
__global__ __launch_bounds__(NTHR, 8) void tail_kernel(
    const float* __restrict__ x1a, const float* __restrict__ x1b,
    float* __restrict__ accTS, float* __restrict__ accTC)
{
    __shared__ v4 hb[74 * 33];          // 39,072 B; T16 paths alias tail:
    __shared__ float red[16];
    float* la = (float*)hb + 3432;      // after T16 hb (26*33 v4 = 3432 fl)
    float* lb = la + 26 * 45;           // 1170 fl each; end 5772 fl < 9768

    const int b = (int)blockIdx.x;
    const size_t X1S = (size_t)256 * 256;

    if (b >= 1248) {                    // L1
        int lbk = b - 1248;
        int cx = lbk & 7, rem = lbk >> 3, cy = rem & 3, nc = rem >> 2;
        const float* p1 = x1a + (size_t)nc * X1S;
        const float* p2 = x1b + (size_t)nc * X1S;
        int tx0 = cx * 32, ty0 = cy * 64;
        hpass_direct<64>(p1, p2, 256, tx0, ty0, hb);
        __syncthreads();
        vpass_reduce<64>(256, tx0, ty0, hb, red, accTS + b, accTC + b);
    } else if (b >= 480) {              // L2
        int lbk = b - 480;
        int cx = lbk & 3, rem = lbk >> 2, cy = rem & 3, nc = rem >> 2;
        const float* p1 = x1a + (size_t)nc * X1S;
        const float* p2 = x1b + (size_t)nc * X1S;
        int tx0 = cx * 32, ty0 = cy * 32;
        hpass_pool1<32>(p1, p2, 128, tx0, ty0, hb);
        __syncthreads();
        vpass_reduce<32>(128, tx0, ty0, hb, red, accTS + b, accTC + b);
    } else if (b >= 96) {               // L3
        int lbk = b - 96;
        int cx = lbk & 1, rem = lbk >> 1, cy = rem & 3, nc = rem >> 2;
        const float* p1 = x1a + (size_t)nc * X1S;
        const float* p2 = x1b + (size_t)nc * X1S;
        int tx0 = cx * 32, ty0 = cy * 16;
        stage_x3(p1, p2, 64, tx0, ty0, la, lb);
        __syncthreads();
        hpass_ldsdir<16>(la, lb, 64, tx0, ty0, hb);
        __syncthreads();
        vpass_reduce<16>(64, tx0, ty0, hb, red, accTS + b, accTC + b);
    } else {                            // L4
        int cy = b & 1, nc = b >> 1;
        const float* p1 = x1a + (size_t)nc * X1S;
        const float* p2 = x1b + (size_t)nc * X1S;
        int tx0 = 0, ty0 = cy * 16;
        stage_x4(p1, p2, 32, tx0, ty0, la, lb);
        __syncthreads();
        hpass_ldsdir<16>(la, lb, 32, tx0, ty0, hb);
        __syncthreads();
        vpass_reduce<16>(32, tx0, ty0, hb, red, accTS + b, accTC + b);
    }
}

// ---- finalize (proven ranges)
__global__ void finalize_kernel(const float* __restrict__ acc0S, const float* __restrict__ acc0C,
                                const float* __restrict__ accTS, const float* __restrict__ accTC,
                                float* __restrict__ out)
{
    __shared__ float sm[10];
    __shared__ float wred[8];
    const int tid  = (int)threadIdx.x;
    const int wave = tid >> 6, lane = tid & 63;
    const int st[5] = {0, 1248, 480, 96, 0};
    const int en[5] = {6144, 2784, 1248, 480, 96};

    for (int srs = 0; srs < 10; ++srs) {
        int l = srs >> 1;
        float p = 0.f;
        if (l == 0) {
            const float* base = (srs & 1) ? acc0C : acc0S;
            for (int i = tid; i < 6144; i += NTHR) p += base[i];
        } else {
            const float* base = (srs & 1) ? accTC : accTS;
            for (int i = st[l] + tid; i < en[l]; i += NTHR) p += base[i];
        }
        #pragma unroll
        for (int o = 32; o > 0; o >>= 1) p += __shfl_down(p, o);
        if (lane == 0) wred[wave] = p;
        __syncthreads();
        if (tid == 0) {
            float t = 0.f;
            #pragma unroll
            for (int w = 0; w < 8; ++w) t += wred[w];
            sm[srs] = t;
        }
        __syncthreads();
    }

    if (tid == 0) {
        const float w[5] = {0.0448f, 0.2856f, 0.3001f, 0.2363f, 0.1333f};
        float ms[5], mc[5];
        for (int l = 0; l < 5; ++l) {
            int oh = (512 >> l) - 10;
            float cnt = 48.f * (float)oh * (float)oh;
            ms[l] = (sm[2 * l] / cnt + 1.f) * 0.5f;
            mc[l] = (sm[2 * l + 1] / cnt + 1.f) * 0.5f;
        }
        float p2 = powf(ms[4], w[4]);
        float r = 1.f;
        for (int i = 0; i < 4; ++i) r *= powf(mc[i], w[i]) * p2;
        out[0] = r;
    }
}

extern "C" void kernel_launch(void* const* d_in, const int* in_sizes, int n_in,
                              void* d_out, int out_size, void* d_ws, size_t ws_size,
                              hipStream_t stream)
{
    (void)in_sizes; (void)n_in; (void)out_size; (void)ws_size;
    const float* img1 = (const float*)d_in[0];
    const float* img2 = (const float*)d_in[1];
    float* out = (float*)d_out;
    float* ws  = (float*)d_ws;

    // workspace (floats): acc0S[6144] acc0C[6144] accTS[2784] accTC[2784]
    //                     X1a X1b
    float* acc0S = ws;
    float* acc0C = acc0S + 6144;
    float* accTS = acc0C + 6144;
    float* accTC = accTS + 2784;
    float* x1a   = accTC + 2784;        // float off 17856 (16B aligned)
    float* x1b   = x1a + (size_t)48 * 256 * 256;

    l0_kernel<<<dim3(16, 8, 48), NTHR, 0, stream>>>(
        img1, img2, x1a, x1b, acc0S, acc0C);
    tail_kernel<<<dim3(2784), NTHR, 0, stream>>>(
        x1a, x1b, accTS, accTC);
    finalize_kernel<<<1, NTHR, 0, stream>>>(
        acc0S, acc0C, accTS, accTC, out);
}